// Round 6
// baseline (357.329 us; speedup 1.0000x reference)
//
#include <hip/hip_runtime.h>
#include <hip/hip_cooperative_groups.h>
#include <math.h>

namespace cg = cooperative_groups;

#define BB 8
#define CDIM 256
#define CCH 64
#define HDIM 64
#define WDIM 64
#define KJ 36           // S*S*K*K
#define EPSV 1e-5f

typedef __attribute__((ext_vector_type(8))) short bf16x8;
typedef __attribute__((ext_vector_type(4))) float f32x4;

__device__ inline unsigned short f2bf(float f) {
    unsigned int u = __float_as_uint(f);
    unsigned int r = (u + 0x7fffu + ((u >> 16) & 1u)) >> 16;
    return (unsigned short)r;
}

// One cooperative kernel, 512 blocks x 256 threads, phases separated by grid.sync().
// LDS union: P1 xds 32768 B | P3 cds 25344 B + st 512 B | P5 ks 9216 B | P2/P4 small.
__global__ __launch_bounds__(256) void mega(const float* __restrict__ x,
                                            const float* __restrict__ w1,
                                            const float* __restrict__ b1,
                                            const float* __restrict__ gamma,
                                            const float* __restrict__ beta,
                                            const float* __restrict__ w2,
                                            const float* __restrict__ b2,
                                            float* __restrict__ out,
                                            float* __restrict__ comp,
                                            float* __restrict__ enc,
                                            float* __restrict__ mx,
                                            float* __restrict__ ivs,
                                            float* __restrict__ rowsumT,
                                            float* __restrict__ rowsqT,
                                            float* __restrict__ stats,
                                            unsigned short* __restrict__ w1b,
                                            unsigned short* __restrict__ w2b) {
    cg::grid_group gridg = cg::this_grid();
    __shared__ __align__(16) char lds[33280];
    const int bid = blockIdx.x;
    const int t = threadIdx.x;

    // ---------------- P0: pack weights to bf16 ----------------
    if (bid < 64) {
        int i = bid * 256 + t;                  // 64*256 = 16384 = CCH*CDIM
        w1b[i] = f2bf(w1[i]);
    } else if (bid < 172) {
        int i = (bid - 64) * 256 + t;           // 108*256 = 27648 = 48*576
        int j = i / 576, k = i % 576;
        int tap = k >> 6, o = k & 63;
        w2b[i] = (j < KJ) ? f2bf(w2[(size_t)(j * CCH + o) * 9 + tap]) : (unsigned short)0;
    }
    gridg.sync();

    // ---------------- P1: 1x1 conv via bf16 MFMA + row stats ----------------
    {
        unsigned short* xds = (unsigned short*)lds;     // [w][c] bf16, swizzled
        const int logical = (bid & 7) * 64 + (bid >> 3);
        const int b = logical >> 6, h = logical & 63;
        const int lane = t & 63, wv = t >> 6;
        const int l15 = lane & 15, g = lane >> 4;

        const float* xr = x + ((size_t)b * CDIM) * (HDIM * WDIM) + (size_t)h * WDIM;
        const int wq = t & 15;
#pragma unroll
        for (int it = 0; it < 8; ++it) {
            int cp = (t >> 4) + it * 16;
            float4 a = *(const float4*)(xr + (size_t)(2 * cp) * (HDIM * WDIM) + wq * 4);
            float4 c = *(const float4*)(xr + (size_t)(2 * cp + 1) * (HDIM * WDIM) + wq * 4);
            float av[4] = {a.x, a.y, a.z, a.w};
            float cv[4] = {c.x, c.y, c.z, c.w};
#pragma unroll
            for (int i = 0; i < 4; ++i) {
                int w = wq * 4 + i;
                unsigned int d = (unsigned int)f2bf(av[i]) | ((unsigned int)f2bf(cv[i]) << 16);
                *(unsigned int*)((char*)xds + w * 512 + ((4 * cp) ^ ((w & 7) << 4))) = d;
            }
        }
        __syncthreads();

        f32x4 acc[4] = {};
        const int orow = wv * 16 + l15;
#pragma unroll
        for (int ks = 0; ks < 8; ++ks) {
            int cb = ks * 64 + g * 16;
            bf16x8 afrag = *(const bf16x8*)((const char*)w1b + orow * 512 + cb);
#pragma unroll
            for (int pt = 0; pt < 4; ++pt) {
                int wrow = pt * 16 + l15;
                bf16x8 bfrag = *(bf16x8*)((char*)xds + wrow * 512 + (cb ^ ((wrow & 7) << 4)));
                acc[pt] = __builtin_amdgcn_mfma_f32_16x16x32_bf16(afrag, bfrag, acc[pt], 0, 0, 0);
            }
        }
#pragma unroll
        for (int r = 0; r < 4; ++r) {
            int o = wv * 16 + g * 4 + r;
            float bias = b1[o];
            float s = 0.f, q = 0.f;
#pragma unroll
            for (int pt = 0; pt < 4; ++pt) {
                float v = acc[pt][r] + bias;
                int w = pt * 16 + l15;
                comp[(((size_t)b * CCH + o) * HDIM + h) * WDIM + w] = v;
                s += v; q += v * v;
            }
#pragma unroll
            for (int off = 1; off < 16; off <<= 1) {
                s += __shfl_xor(s, off, 64);
                q += __shfl_xor(q, off, 64);
            }
            if (l15 == 0) {
                rowsumT[(size_t)o * 512 + logical] = s;
                rowsqT[(size_t)o * 512 + logical] = q;
            }
        }
    }
    gridg.sync();

    // ---------------- P2: finalize BN stats (blocks 0..63) ----------------
    if (bid < 64) {
        const int o = bid;
        float s = rowsumT[(size_t)o * 512 + t] + rowsumT[(size_t)o * 512 + t + 256];
        float q = rowsqT[(size_t)o * 512 + t] + rowsqT[(size_t)o * 512 + t + 256];
#pragma unroll
        for (int off = 32; off >= 1; off >>= 1) {
            s += __shfl_xor(s, off, 64);
            q += __shfl_xor(q, off, 64);
        }
        float* ls = (float*)lds;                // [4] + [4]
        const int wave = t >> 6, lane = t & 63;
        if (lane == 0) { ls[wave] = s; ls[4 + wave] = q; }
        __syncthreads();
        if (t == 0) {
            float S = ls[0] + ls[1] + ls[2] + ls[3];
            float Q = ls[4] + ls[5] + ls[6] + ls[7];
            const float N = (float)(BB * HDIM * WDIM);
            float mu = S / N;
            float var = Q / N - mu * mu;
            float a = rsqrtf(var + EPSV) * gamma[o];
            stats[o] = a;
            stats[CCH + o] = beta[o] - mu * a;
        }
    }
    gridg.sync();

    // ---------------- P3: BN/ReLU + 3x3 conv via bf16 MFMA (implicit GEMM) ----------------
    {
        unsigned short* cds = (unsigned short*)lds;     // [R=dy*66+wcol][o] bf16, 25344 B
        float* st = (float*)(lds + 25856);              // 512 B
        const int logical = (bid & 7) * 64 + (bid >> 3);
        const int b = logical >> 6, h = logical & 63;
        const int lane = t & 63, wv = t >> 6;
        const int l15 = lane & 15, g = lane >> 4;

        if (t < 2 * CCH) st[t] = stats[t];
        __syncthreads();

        for (int idx = t; idx < 3 * 32 * WDIM; idx += 256) {
            int dy = idx >> 11, rem = idx & 2047;
            int op = rem >> 6, w = rem & 63;
            int hh = h + dy - 1;
            unsigned int d = 0;
            if (hh >= 0 && hh < HDIM) {
                int o0 = 2 * op;
                float v0 = fmaxf(comp[(((size_t)b * CCH + o0) * HDIM + hh) * WDIM + w] * st[o0] + st[CCH + o0], 0.f);
                float v1 = fmaxf(comp[(((size_t)b * CCH + o0 + 1) * HDIM + hh) * WDIM + w] * st[o0 + 1] + st[CCH + o0 + 1], 0.f);
                d = (unsigned int)f2bf(v0) | ((unsigned int)f2bf(v1) << 16);
            }
            int R = dy * 66 + (w + 1);
            *(unsigned int*)((char*)cds + R * 128 + ((4 * op) ^ ((R & 7) << 4))) = d;
        }
        for (int idx = t; idx < 3 * 2 * 32; idx += 256) {
            int dy = idx >> 6, rem = idx & 63;
            int col = (rem >> 5) ? 65 : 0, op = rem & 31;
            int R = dy * 66 + col;
            *(unsigned int*)((char*)cds + R * 128 + ((4 * op) ^ ((R & 7) << 4))) = 0u;
        }
        __syncthreads();

        f32x4 acc3[3] = {};
        const int px = wv * 16 + l15;
#pragma unroll
        for (int ks = 0; ks < 18; ++ks) {
            int k0 = ks * 32 + g * 8;
            int dy = k0 / 192, rm = k0 % 192;
            int dx = rm >> 6, o0 = rm & 63;
            int R = dy * 66 + px + dx;
            bf16x8 bfrag = *(bf16x8*)((char*)cds + R * 128 + ((2 * o0) ^ ((R & 7) << 4)));
#pragma unroll
            for (int jt = 0; jt < 3; ++jt) {
                int j = jt * 16 + l15;
                bf16x8 afrag = *(const bf16x8*)((const char*)w2b + (size_t)(j * 576 + k0) * 2);
                acc3[jt] = __builtin_amdgcn_mfma_f32_16x16x32_bf16(afrag, bfrag, acc3[jt], 0, 0, 0);
            }
        }
#pragma unroll
        for (int jt = 0; jt < 3; ++jt) {
#pragma unroll
            for (int r = 0; r < 4; ++r) {
                int j = jt * 16 + g * 4 + r;
                if (j < KJ) {
                    float v = acc3[jt][r] + b2[j];
                    enc[(((size_t)b * KJ + j) * HDIM + h) * WDIM + px] = v;
                }
            }
        }
    }
    gridg.sync();

    // ---------------- P4: softmax column stats over H (blocks 0..287) ----------------
    if (bid < BB * KJ) {
        const int b = bid & 7, j = bid >> 3;
        const int bj = b * KJ + j;
        const int w = t & 63, q = t >> 6;
        const float* p = enc + (size_t)bj * HDIM * WDIM + (size_t)q * 16 * WDIM + w;
        float v[16];
        float lm = -1e30f;
#pragma unroll
        for (int i = 0; i < 16; ++i) { v[i] = p[i * WDIM]; lm = fmaxf(lm, v[i]); }

        float (*red)[WDIM] = (float(*)[WDIM])lds;       // [4][64]
        red[q][w] = lm;
        __syncthreads();
        float gm = fmaxf(fmaxf(red[0][w], red[1][w]), fmaxf(red[2][w], red[3][w]));
        __syncthreads();
        float lsum = 0.f;
#pragma unroll
        for (int i = 0; i < 16; ++i) lsum += __expf(v[i] - gm);
        red[q][w] = lsum;
        __syncthreads();
        if (q == 0) {
            float s = red[0][w] + red[1][w] + red[2][w] + red[3][w];
            mx[(size_t)bj * WDIM + w] = gm;
            ivs[(size_t)bj * WDIM + w] = 1.f / s;
        }
    }
    gridg.sync();

    // ---------------- P5: CARAFE gather + scatter (64 ch/thread) ----------------
    {
        float (*ks)[WDIM] = (float(*)[WDIM])lds;        // [36][64]
        const int logical = (bid & 7) * 64 + (bid >> 3);
        const int b = logical >> 6, h = logical & 63;

        for (int e = t; e < KJ * WDIM; e += 256) {
            int j = e >> 6, w = e & 63;
            size_t bjw = ((size_t)b * KJ + j) * WDIM + w;
            float raw = enc[((size_t)b * KJ + j) * HDIM * WDIM + (size_t)h * WDIM + w];
            ks[j][w] = __expf(raw - mx[bjw]) * ivs[bjw];
        }
        __syncthreads();

        const int w = t & 63;
        const int cgr = t >> 6;                         // 4 groups of 64 channels

        float kern[KJ];
#pragma unroll
        for (int j = 0; j < KJ; ++j) kern[j] = ks[j][w];

        const int hm1 = (h > 0) ? h - 1 : 0, hp1 = (h < 63) ? h + 1 : 63;
        const int wm1 = (w > 0) ? w - 1 : 0, wp1 = (w < 63) ? w + 1 : 63;

        for (int ci = 0; ci < 64; ++ci) {
            int c = cgr * 64 + ci;
            const float* xb = x + ((size_t)b * CDIM + c) * HDIM * WDIM;
            float r0 = xb[hm1 * WDIM + w];
            float r1 = xb[h   * WDIM + w];
            float r2 = xb[hp1 * WDIM + w];
            float tap[9];
            tap[0] = __shfl(r0, wm1, 64); tap[1] = r0; tap[2] = __shfl(r0, wp1, 64);
            tap[3] = __shfl(r1, wm1, 64); tap[4] = r1; tap[5] = __shfl(r1, wp1, 64);
            tap[6] = __shfl(r2, wm1, 64); tap[7] = r2; tap[8] = __shfl(r2, wp1, 64);

            float o0 = 0.f, o1 = 0.f, o2 = 0.f, o3 = 0.f;
#pragma unroll
            for (int k = 0; k < 9; ++k) {
                float tv = tap[k];
                o0 += tv * kern[0 * 9 + k];
                o1 += tv * kern[1 * 9 + k];
                o2 += tv * kern[2 * 9 + k];
                o3 += tv * kern[3 * 9 + k];
            }
            // out[b, s*64 + c/4, 2h + ((c>>1)&1), (c&1)*64 + w]
            int c2b = c >> 2;
            int hs = 2 * h + ((c >> 1) & 1);
            int wsx = (c & 1) * 64 + w;
            size_t base = ((size_t)b * CDIM) * (128 * 128) + (size_t)hs * 128 + wsx;
            out[base + (size_t)(0 * 64 + c2b) * (128 * 128)] = o0;
            out[base + (size_t)(1 * 64 + c2b) * (128 * 128)] = o1;
            out[base + (size_t)(2 * 64 + c2b) * (128 * 128)] = o2;
            out[base + (size_t)(3 * 64 + c2b) * (128 * 128)] = o3;
        }
    }
}

extern "C" void kernel_launch(void* const* d_in, const int* in_sizes, int n_in,
                              void* d_out, int out_size, void* d_ws, size_t ws_size,
                              hipStream_t stream) {
    const float* x     = (const float*)d_in[0];
    const float* w1    = (const float*)d_in[1];
    const float* b1    = (const float*)d_in[2];
    const float* gamma = (const float*)d_in[3];
    const float* beta  = (const float*)d_in[4];
    const float* w2    = (const float*)d_in[5];
    const float* b2    = (const float*)d_in[6];
    float* out = (float*)d_out;

    char* ws = (char*)d_ws;
    float* comp         = (float*)(ws);                        // 8,388,608 B
    float* enc          = (float*)(ws + 8388608);              // 4,718,592 -> 13,107,200
    float* mx           = (float*)(ws + 13107200);             // 73,728 -> 13,180,928
    float* ivs          = (float*)(ws + 13180928);             // 73,728 -> 13,254,656
    float* rowsumT      = (float*)(ws + 13254656);             // 131,072 -> 13,385,728
    float* rowsqT       = (float*)(ws + 13385728);             // 131,072 -> 13,516,800
    float* stats        = (float*)(ws + 13516800);             // 512 -> 13,517,312
    unsigned short* w1b = (unsigned short*)(ws + 13517312);    // 32,768 -> 13,550,080
    unsigned short* w2b = (unsigned short*)(ws + 13550080);    // 55,296 -> 13,605,376

    void* args[] = {(void*)&x, (void*)&w1, (void*)&b1, (void*)&gamma, (void*)&beta,
                    (void*)&w2, (void*)&b2, (void*)&out, (void*)&comp, (void*)&enc,
                    (void*)&mx, (void*)&ivs, (void*)&rowsumT, (void*)&rowsqT,
                    (void*)&stats, (void*)&w1b, (void*)&w2b};
    hipLaunchCooperativeKernel((const void*)mega, dim3(512), dim3(256), args, 0, stream);
}

// Round 7
// 76.326 us; speedup vs baseline: 4.6816x; 4.6816x over previous
//
#include <hip/hip_runtime.h>
#include <math.h>

#define BB 8
#define CDIM 256
#define CCH 64
#define HDIM 64
#define WDIM 64
#define KJ 36           // S*S*K*K
#define EPSV 1e-5f

typedef __attribute__((ext_vector_type(8))) short bf16x8;
typedef __attribute__((ext_vector_type(4))) float f32x4;

__device__ inline unsigned short f2bf(float f) {
    unsigned int u = __float_as_uint(f);
    unsigned int r = (u + 0x7fffu + ((u >> 16) & 1u)) >> 16;
    return (unsigned short)r;
}

// ---------------- K1: 1x1 conv via bf16 MFMA (w1 cvt in-register) + row stats
//                   + folded w2->bf16 pack (first 108 blocks); XCD-swizzled ----------------
__global__ __launch_bounds__(256) void k1_mfma(const float* __restrict__ x,
                                               const float* __restrict__ w1,
                                               const float* __restrict__ b1,
                                               const float* __restrict__ w2,
                                               unsigned short* __restrict__ w2b,
                                               float* __restrict__ comp,
                                               float* __restrict__ rowsumT,
                                               float* __restrict__ rowsqT) {
    __shared__ __align__(16) unsigned short xds[WDIM * CDIM];   // [w][c] bf16, swizzled, 32 KB
    const int bid = blockIdx.x;                 // 512 blocks, chunked XCD swizzle
    const int t = threadIdx.x;

    // folded w2 pack: blocks 0..107 each convert 256 elements (48*576 = 27648 total)
    {
        int i = bid * 256 + t;
        if (i < 48 * 576) {
            int j = i / 576, k = i % 576;
            int tap = k >> 6, o = k & 63;
            w2b[i] = (j < KJ) ? f2bf(w2[(size_t)(j * CCH + o) * 9 + tap]) : (unsigned short)0;
        }
    }

    const int logical = (bid & 7) * 64 + (bid >> 3);
    const int b = logical >> 6, h = logical & 63;
    const int lane = t & 63, wv = t >> 6;
    const int l15 = lane & 15, g = lane >> 4;

    // stage x[b,:,h,:] -> bf16 LDS [w][c], row stride 512 B, byte ^= (w&7)<<4
    const float* xr = x + ((size_t)b * CDIM) * (HDIM * WDIM) + (size_t)h * WDIM;
    const int wq = t & 15;
#pragma unroll
    for (int it = 0; it < 8; ++it) {
        int cp = (t >> 4) + it * 16;
        float4 a = *(const float4*)(xr + (size_t)(2 * cp) * (HDIM * WDIM) + wq * 4);
        float4 c = *(const float4*)(xr + (size_t)(2 * cp + 1) * (HDIM * WDIM) + wq * 4);
        float av[4] = {a.x, a.y, a.z, a.w};
        float cv[4] = {c.x, c.y, c.z, c.w};
#pragma unroll
        for (int i = 0; i < 4; ++i) {
            int w = wq * 4 + i;
            unsigned int d = (unsigned int)f2bf(av[i]) | ((unsigned int)f2bf(cv[i]) << 16);
            *(unsigned int*)((char*)xds + w * 512 + ((4 * cp) ^ ((w & 7) << 4))) = d;
        }
    }
    __syncthreads();

    // MFMA: wave wv owns o-tile [wv*16, +16); 4 px-tiles; K=256 in 8 steps
    f32x4 acc[4] = {};
    const int orow = wv * 16 + l15;
#pragma unroll
    for (int ks = 0; ks < 8; ++ks) {
        const float* wp = w1 + (size_t)orow * CDIM + ks * 32 + g * 8;
        float4 wa = *(const float4*)wp;
        float4 wb = *(const float4*)(wp + 4);
        bf16x8 afrag;
        afrag[0] = (short)f2bf(wa.x); afrag[1] = (short)f2bf(wa.y);
        afrag[2] = (short)f2bf(wa.z); afrag[3] = (short)f2bf(wa.w);
        afrag[4] = (short)f2bf(wb.x); afrag[5] = (short)f2bf(wb.y);
        afrag[6] = (short)f2bf(wb.z); afrag[7] = (short)f2bf(wb.w);
        int cb = ks * 64 + g * 16;
#pragma unroll
        for (int pt = 0; pt < 4; ++pt) {
            int wrow = pt * 16 + l15;
            bf16x8 bfrag = *(bf16x8*)((char*)xds + wrow * 512 + (cb ^ ((wrow & 7) << 4)));
            acc[pt] = __builtin_amdgcn_mfma_f32_16x16x32_bf16(afrag, bfrag, acc[pt], 0, 0, 0);
        }
    }

    // epilogue: D[o = wv*16 + g*4 + r][w = pt*16 + l15]; bias, store, row stats
#pragma unroll
    for (int r = 0; r < 4; ++r) {
        int o = wv * 16 + g * 4 + r;
        float bias = b1[o];
        float s = 0.f, q = 0.f;
#pragma unroll
        for (int pt = 0; pt < 4; ++pt) {
            float v = acc[pt][r] + bias;
            int w = pt * 16 + l15;
            comp[(((size_t)b * CCH + o) * HDIM + h) * WDIM + w] = v;
            s += v; q += v * v;
        }
#pragma unroll
        for (int off = 1; off < 16; off <<= 1) {
            s += __shfl_xor(s, off, 64);
            q += __shfl_xor(q, off, 64);
        }
        if (l15 == 0) {
            rowsumT[(size_t)o * 512 + logical] = s;
            rowsqT[(size_t)o * 512 + logical] = q;
        }
    }
}

// ---------------- K2: finalize BN stats, one block per channel ----------------
__global__ __launch_bounds__(256) void k2_stats(const float* __restrict__ rowsumT,
                                                const float* __restrict__ rowsqT,
                                                const float* __restrict__ gamma,
                                                const float* __restrict__ beta,
                                                float* __restrict__ stats) {
    const int o = blockIdx.x;                   // 64 blocks
    const int t = threadIdx.x;
    float s = rowsumT[(size_t)o * 512 + t] + rowsumT[(size_t)o * 512 + t + 256];
    float q = rowsqT[(size_t)o * 512 + t] + rowsqT[(size_t)o * 512 + t + 256];
#pragma unroll
    for (int off = 32; off >= 1; off >>= 1) {
        s += __shfl_xor(s, off, 64);
        q += __shfl_xor(q, off, 64);
    }
    __shared__ float ls[4], lq[4];
    const int wave = t >> 6, lane = t & 63;
    if (lane == 0) { ls[wave] = s; lq[wave] = q; }
    __syncthreads();
    if (t == 0) {
        float S = ls[0] + ls[1] + ls[2] + ls[3];
        float Q = lq[0] + lq[1] + lq[2] + lq[3];
        const float N = (float)(BB * HDIM * WDIM);
        float mu = S / N;
        float var = Q / N - mu * mu;
        float a = rsqrtf(var + EPSV) * gamma[o];
        stats[o] = a;
        stats[CCH + o] = beta[o] - mu * a;
    }
}

// ---------------- K3: BN/ReLU + 3x3 conv via bf16 MFMA (implicit GEMM), XCD-swizzled ----------------
__global__ __launch_bounds__(256) void k3_mfma(const float* __restrict__ comp,
                                               const float* __restrict__ stats,
                                               const unsigned short* __restrict__ w2b,
                                               const float* __restrict__ b2,
                                               float* __restrict__ enc) {
    __shared__ __align__(16) unsigned short cds[3 * 66 * CCH];  // [R=dy*66+wcol][o] bf16, 25 KB
    __shared__ float st[2 * CCH];
    const int bid = blockIdx.x;                 // 512 blocks, chunked XCD swizzle
    const int logical = (bid & 7) * 64 + (bid >> 3);
    const int b = logical >> 6, h = logical & 63;
    const int t = threadIdx.x;
    const int lane = t & 63, wv = t >> 6;
    const int l15 = lane & 15, g = lane >> 4;

    if (t < 2 * CCH) st[t] = stats[t];
    __syncthreads();

    for (int idx = t; idx < 3 * 32 * WDIM; idx += 256) {
        int dy = idx >> 11, rem = idx & 2047;
        int op = rem >> 6, w = rem & 63;
        int hh = h + dy - 1;
        unsigned int d = 0;
        if (hh >= 0 && hh < HDIM) {
            int o0 = 2 * op;
            float v0 = fmaxf(comp[(((size_t)b * CCH + o0) * HDIM + hh) * WDIM + w] * st[o0] + st[CCH + o0], 0.f);
            float v1 = fmaxf(comp[(((size_t)b * CCH + o0 + 1) * HDIM + hh) * WDIM + w] * st[o0 + 1] + st[CCH + o0 + 1], 0.f);
            d = (unsigned int)f2bf(v0) | ((unsigned int)f2bf(v1) << 16);
        }
        int R = dy * 66 + (w + 1);
        *(unsigned int*)((char*)cds + R * 128 + ((4 * op) ^ ((R & 7) << 4))) = d;
    }
    for (int idx = t; idx < 3 * 2 * 32; idx += 256) {
        int dy = idx >> 6, rem = idx & 63;
        int col = (rem >> 5) ? 65 : 0, op = rem & 31;
        int R = dy * 66 + col;
        *(unsigned int*)((char*)cds + R * 128 + ((4 * op) ^ ((R & 7) << 4))) = 0u;
    }
    __syncthreads();

    f32x4 acc3[3] = {};
    const int px = wv * 16 + l15;
#pragma unroll
    for (int ks = 0; ks < 18; ++ks) {
        int k0 = ks * 32 + g * 8;
        int dy = k0 / 192, rm = k0 % 192;
        int dx = rm >> 6, o0 = rm & 63;
        int R = dy * 66 + px + dx;
        bf16x8 bfrag = *(bf16x8*)((char*)cds + R * 128 + ((2 * o0) ^ ((R & 7) << 4)));
#pragma unroll
        for (int jt = 0; jt < 3; ++jt) {
            int j = jt * 16 + l15;
            bf16x8 afrag = *(const bf16x8*)((const char*)w2b + (size_t)(j * 576 + k0) * 2);
            acc3[jt] = __builtin_amdgcn_mfma_f32_16x16x32_bf16(afrag, bfrag, acc3[jt], 0, 0, 0);
        }
    }
#pragma unroll
    for (int jt = 0; jt < 3; ++jt) {
#pragma unroll
        for (int r = 0; r < 4; ++r) {
            int j = jt * 16 + g * 4 + r;
            if (j < KJ) {
                float v = acc3[jt][r] + b2[j];
                enc[(((size_t)b * KJ + j) * HDIM + h) * WDIM + px] = v;
            }
        }
    }
}

// ---------------- K4: softmax column stats over H per (b,j,w) ----------------
__global__ __launch_bounds__(256) void k4_smstats(const float* __restrict__ enc,
                                                  float* __restrict__ mx,
                                                  float* __restrict__ ivs) {
    const int bid = blockIdx.x;                 // 288 = 8*36
    const int b = bid & 7, j = bid >> 3;
    const int bj = b * KJ + j;
    const int t = threadIdx.x;
    const int w = t & 63, q = t >> 6;
    const float* p = enc + (size_t)bj * HDIM * WDIM + (size_t)q * 16 * WDIM + w;
    float v[16];
    float lm = -1e30f;
#pragma unroll
    for (int i = 0; i < 16; ++i) { v[i] = p[i * WDIM]; lm = fmaxf(lm, v[i]); }

    __shared__ float red[4][WDIM];
    red[q][w] = lm;
    __syncthreads();
    float gm = fmaxf(fmaxf(red[0][w], red[1][w]), fmaxf(red[2][w], red[3][w]));
    __syncthreads();
    float ls = 0.f;
#pragma unroll
    for (int i = 0; i < 16; ++i) ls += __expf(v[i] - gm);
    red[q][w] = ls;
    __syncthreads();
    if (q == 0) {
        float s = red[0][w] + red[1][w] + red[2][w] + red[3][w];
        mx[(size_t)bj * WDIM + w] = gm;
        ivs[(size_t)bj * WDIM + w] = 1.f / s;
    }
}

// ---------------- K5: CARAFE h-pair (2 output rows/block), 1024 blocks, XCD-swizzled ----------------
__global__ __launch_bounds__(256) void k5_carafe(const float* __restrict__ x,
                                                 const float* __restrict__ enc,
                                                 const float* __restrict__ mx,
                                                 const float* __restrict__ ivs,
                                                 float* __restrict__ out) {
    __shared__ float ks2[2][KJ][WDIM];          // 18.4 KB
    const int bid = blockIdx.x;                 // 1024 blocks, chunked XCD swizzle
    const int logical = (bid & 7) * 128 + (bid >> 3);
    const int b = logical >> 7;
    const int rem = logical & 127;
    const int hp = rem >> 2, cg = rem & 3;      // h-pair 0..31, 64-ch group 0..3
    const int h0 = hp * 2;
    const int t = threadIdx.x;

    for (int e = t; e < 2 * KJ * WDIM; e += 256) {
        int hh = e / (KJ * WDIM);
        int r2 = e % (KJ * WDIM);
        int j = r2 >> 6, w = r2 & 63;
        size_t bjw = ((size_t)b * KJ + j) * WDIM + w;
        float raw = enc[((size_t)b * KJ + j) * (HDIM * WDIM) + (size_t)(h0 + hh) * WDIM + w];
        ks2[hh][j][w] = __expf(raw - mx[bjw]) * ivs[bjw];
    }
    __syncthreads();

    const int w = t & 63;
    const int sub = t >> 6;                     // wave-uniform 16-ch sub-chunk

    float kern[2][KJ];
#pragma unroll
    for (int hh = 0; hh < 2; ++hh)
#pragma unroll
        for (int j = 0; j < KJ; ++j) kern[hh][j] = ks2[hh][j][w];

    const int rm1 = (h0 > 0) ? h0 - 1 : 0;
    const int rp2 = (h0 + 2 < HDIM) ? h0 + 2 : HDIM - 1;
    const int wm1 = (w > 0) ? w - 1 : 0, wp1 = (w < 63) ? w + 1 : 63;

    for (int ci = 0; ci < 16; ++ci) {
        int c = cg * 64 + sub * 16 + ci;
        const float* xb = x + ((size_t)b * CDIM + c) * (HDIM * WDIM);
        float r[4], tl[4], tr[4];
        r[0] = xb[rm1 * WDIM + w];
        r[1] = xb[h0 * WDIM + w];
        r[2] = xb[(h0 + 1) * WDIM + w];
        r[3] = xb[rp2 * WDIM + w];
#pragma unroll
        for (int i = 0; i < 4; ++i) {
            tl[i] = __shfl(r[i], wm1, 64);
            tr[i] = __shfl(r[i], wp1, 64);
        }

        int c2b = c >> 2;
        int codd = (c >> 1) & 1;
        int wsx = (c & 1) * 64 + w;
#pragma unroll
        for (int hh = 0; hh < 2; ++hh) {
            float o0 = 0.f, o1 = 0.f, o2 = 0.f, o3 = 0.f;
#pragma unroll
            for (int dy = 0; dy < 3; ++dy) {
                int rr = hh + dy;
                float a = tl[rr], m = r[rr], cc = tr[rr];
                int k = dy * 3;
                o0 += a * kern[hh][0 * 9 + k] + m * kern[hh][0 * 9 + k + 1] + cc * kern[hh][0 * 9 + k + 2];
                o1 += a * kern[hh][1 * 9 + k] + m * kern[hh][1 * 9 + k + 1] + cc * kern[hh][1 * 9 + k + 2];
                o2 += a * kern[hh][2 * 9 + k] + m * kern[hh][2 * 9 + k + 1] + cc * kern[hh][2 * 9 + k + 2];
                o3 += a * kern[hh][3 * 9 + k] + m * kern[hh][3 * 9 + k + 1] + cc * kern[hh][3 * 9 + k + 2];
            }
            // out[b, s*64 + c/4, 2h + ((c>>1)&1), (c&1)*64 + w]
            int hs = 2 * (h0 + hh) + codd;
            size_t base = ((size_t)b * CDIM) * (128 * 128) + (size_t)hs * 128 + wsx;
            __builtin_nontemporal_store(o0, &out[base + (size_t)(0 * 64 + c2b) * (128 * 128)]);
            __builtin_nontemporal_store(o1, &out[base + (size_t)(1 * 64 + c2b) * (128 * 128)]);
            __builtin_nontemporal_store(o2, &out[base + (size_t)(2 * 64 + c2b) * (128 * 128)]);
            __builtin_nontemporal_store(o3, &out[base + (size_t)(3 * 64 + c2b) * (128 * 128)]);
        }
    }
}

extern "C" void kernel_launch(void* const* d_in, const int* in_sizes, int n_in,
                              void* d_out, int out_size, void* d_ws, size_t ws_size,
                              hipStream_t stream) {
    const float* x     = (const float*)d_in[0];
    const float* w1    = (const float*)d_in[1];
    const float* b1    = (const float*)d_in[2];
    const float* gamma = (const float*)d_in[3];
    const float* beta  = (const float*)d_in[4];
    const float* w2    = (const float*)d_in[5];
    const float* b2    = (const float*)d_in[6];
    float* out = (float*)d_out;

    char* ws = (char*)d_ws;
    float* comp         = (float*)(ws);                        // 8,388,608 B
    float* enc          = (float*)(ws + 8388608);              // 4,718,592 -> 13,107,200
    float* mx           = (float*)(ws + 13107200);             // 73,728 -> 13,180,928
    float* ivs          = (float*)(ws + 13180928);             // 73,728 -> 13,254,656
    float* rowsumT      = (float*)(ws + 13254656);             // 131,072 -> 13,385,728
    float* rowsqT       = (float*)(ws + 13385728);             // 131,072 -> 13,516,800
    float* stats        = (float*)(ws + 13516800);             // 512 -> 13,517,312
    unsigned short* w2b = (unsigned short*)(ws + 13517312);    // 55,296 -> 13,572,608

    hipLaunchKernelGGL(k1_mfma,    dim3(BB * HDIM),     dim3(256), 0, stream, x, w1, b1, w2, w2b, comp, rowsumT, rowsqT);
    hipLaunchKernelGGL(k2_stats,   dim3(CCH),           dim3(256), 0, stream, rowsumT, rowsqT, gamma, beta, stats);
    hipLaunchKernelGGL(k3_mfma,    dim3(BB * HDIM),     dim3(256), 0, stream, comp, stats, w2b, b2, enc);
    hipLaunchKernelGGL(k4_smstats, dim3(BB * KJ),       dim3(256), 0, stream, enc, mx, ivs);
    hipLaunchKernelGGL(k5_carafe,  dim3(BB * HDIM * 2), dim3(256), 0, stream, x, enc, mx, ivs, out);
}